// Round 4
// baseline (262.468 us; speedup 1.0000x reference)
//
#include <hip/hip_runtime.h>
#include <math.h>

// SPU transformer: pure elementwise over N rows. R1 findings: 101 us/dispatch,
// HBM 1.96 TB/s (25%), FETCH = exactly 2/4 input arrays (L3 serves the rest
// across replays), WRITE = output. Working set 320 MiB vs 256 MiB L3 -> the
// output stream evicts inputs from L3. Fix: (1) non-temporal stores so the
// output does not allocate in L2/L3; (2) 2 float4 per thread for 8
// outstanding loads/wave. R2: __builtin_nontemporal_store needs a native
// clang vector type -> ext_vector_type(4). R3: references can't bind to
// vector elements -> compute in scalars, assemble the vector after.

typedef float nfloat4 __attribute__((ext_vector_type(4)));

__device__ __forceinline__ float spu_f(float x) {
    // x >= 0: x*x - 0.5 ; x < 0: sigmoid(-x) - 1 = 1/(1+e^x) - 1
    if (x >= 0.0f) {
        return x * x - 0.5f;
    } else {
        return 1.0f / (1.0f + __expf(x)) - 1.0f;
    }
}

__device__ __forceinline__ void spu_row(float l, float u,
                                        float p1l, float p1u,
                                        float q1l, float q1u,
                                        float b0l, float b0u,
                                        float& out_lo, float& out_hi) {
    const float sl = spu_f(l);
    const float su = spu_f(u);

    const bool neg   = (u <= 0.0f);
    const bool pos   = (l >= 0.0f);
    const bool cross = !(neg || pos);

    const float all_slopes = (su - sl) / (u - l);

    const float s0 = neg ? all_slopes : 0.0f;
    const float s1 = (pos || cross) ? all_slopes : 0.0f;

    const bool neg_slope = (all_slopes < 0.0f);
    float lo = neg_slope ? su : sl;
    float hi = neg_slope ? sl : su;
    lo = cross ? -0.5f : lo;

    float sh1 = fmaf(-s1, u, su);  // su - s1*u
    float sh0 = fmaf(-s0, l, sl);  // sl - s0*l
    sh0 = cross ? -0.5f : sh0;
    sh1 = neg ? sl : sh1;

    const float s1p = fmaxf(s1, 0.0f), s1n = fminf(s1, 0.0f);
    const float s0p = fmaxf(s0, 0.0f), s0n = fminf(s0, 0.0f);

    const float UBM = s1p * p1u + s1n * p1l;
    const float UBV = s1p * q1u + sh1 + s1n * q1l;
    const float LBM = s0p * p1l + s0n * p1u;
    const float LBV = s0n * q1l + sh0 + s0p * q1u;

    const float lower = fmaxf(LBM, 0.0f) * b0l + fminf(LBM, 0.0f) * b0u + LBV;
    const float upper = fmaxf(UBM, 0.0f) * b0u + fminf(UBM, 0.0f) * b0l + UBV;

    out_lo = (lower > lo) ? lower : lo;
    out_hi = (upper < hi) ? upper : hi;
}

__device__ __forceinline__ nfloat4 spu_quad(const float4 b, const float4 sp,
                                            const float4 sh, const float4 bp) {
    float o0, o1, o2, o3;
    spu_row(b.x, b.y, sp.x, sp.y, sh.x, sh.y, bp.x, bp.y, o0, o1);
    spu_row(b.z, b.w, sp.z, sp.w, sh.z, sh.w, bp.z, bp.w, o2, o3);
    nfloat4 o;
    o.x = o0; o.y = o1; o.z = o2; o.w = o3;
    return o;
}

__global__ __launch_bounds__(256) void SPUTransformer_62002147885333_kernel(
    const float4* __restrict__ bounds,
    const float4* __restrict__ slopes_prev,
    const float4* __restrict__ shifts_prev,
    const float4* __restrict__ bounds_prev,
    nfloat4* __restrict__ out,
    int npairs)  // npairs = N/2; one float4 = two (l,u) rows
{
    // Two coalesced float4 indices per thread: i0 and i0 + blockDim.
    const int i0 = blockIdx.x * (blockDim.x * 2) + threadIdx.x;
    const int i1 = i0 + blockDim.x;

    if (i1 < npairs) {
        // Issue all 8 loads before any compute (8 outstanding vmem/wave).
        const float4 b0  = bounds[i0];
        const float4 b1  = bounds[i1];
        const float4 sp0 = slopes_prev[i0];
        const float4 sp1 = slopes_prev[i1];
        const float4 sh0 = shifts_prev[i0];
        const float4 sh1 = shifts_prev[i1];
        const float4 bp0 = bounds_prev[i0];
        const float4 bp1 = bounds_prev[i1];

        const nfloat4 o0 = spu_quad(b0, sp0, sh0, bp0);
        const nfloat4 o1 = spu_quad(b1, sp1, sh1, bp1);

        // Output is never re-read: keep it out of L2/L3 so it does not evict
        // the input arrays (320 MiB working set vs 256 MiB Infinity Cache).
        __builtin_nontemporal_store(o0, &out[i0]);
        __builtin_nontemporal_store(o1, &out[i1]);
    } else if (i0 < npairs) {
        const float4 b  = bounds[i0];
        const float4 sp = slopes_prev[i0];
        const float4 sh = shifts_prev[i0];
        const float4 bp = bounds_prev[i0];
        const nfloat4 o = spu_quad(b, sp, sh, bp);
        __builtin_nontemporal_store(o, &out[i0]);
    }
}

extern "C" void kernel_launch(void* const* d_in, const int* in_sizes, int n_in,
                              void* d_out, int out_size, void* d_ws, size_t ws_size,
                              hipStream_t stream) {
    // Inputs (setup_inputs order): bounds (N,2), slopes_prev (N,2),
    // shifts_prev (N,2), bounds_prev (N,2) -- all float32.
    const float4* bounds      = (const float4*)d_in[0];
    const float4* slopes_prev = (const float4*)d_in[1];
    const float4* shifts_prev = (const float4*)d_in[2];
    const float4* bounds_prev = (const float4*)d_in[3];
    nfloat4* out = (nfloat4*)d_out;

    const int n_rows = in_sizes[0] / 2;   // N
    const int npairs = n_rows / 2;        // N even (8388608)

    const int block = 256;
    const int per_block = block * 2;      // 2 float4 per thread
    const int grid = (npairs + per_block - 1) / per_block;

    SPUTransformer_62002147885333_kernel<<<grid, block, 0, stream>>>(
        bounds, slopes_prev, shifts_prev, bounds_prev, out, npairs);
}

// Round 5
// 233.305 us; speedup vs baseline: 1.1250x; 1.1250x over previous
//
#include <hip/hip_runtime.h>
#include <math.h>

// SPU transformer: pure elementwise, 32B read + 8B write per row, N=8.4M.
// R1: baseline float4 kernel, 101 us, HBM 1.96 TB/s, FETCH = 131 MB (2 of 4
//     inputs; L3 serves the rest), logical rate 3.3 TB/s.
// R4: NT store + 2 float4/thread: FETCH unchanged, 110 us (worse). ILP and
//     store policy are NOT the lever. Theory revised: the L3-hit read path
//     serves 134 MB at only ~1.3 TB/s -- slower than HBM streaming. This
//     round: nontemporal LOADS on all inputs to bypass cache allocation and
//     make this a pure 5-stream HBM kernel (like the 6.29 TB/s copy bench).
// Predicted: FETCH -> ~262 MB, dur -> ~55-70 us, hbm_gbps -> ~5-6 TB/s.

typedef float nfloat4 __attribute__((ext_vector_type(4)));

__device__ __forceinline__ float spu_f(float x) {
    // x >= 0: x*x - 0.5 ; x < 0: sigmoid(-x) - 1 = 1/(1+e^x) - 1
    if (x >= 0.0f) {
        return x * x - 0.5f;
    } else {
        return 1.0f / (1.0f + __expf(x)) - 1.0f;
    }
}

__device__ __forceinline__ void spu_row(float l, float u,
                                        float p1l, float p1u,
                                        float q1l, float q1u,
                                        float b0l, float b0u,
                                        float& out_lo, float& out_hi) {
    const float sl = spu_f(l);
    const float su = spu_f(u);

    const bool neg   = (u <= 0.0f);
    const bool pos   = (l >= 0.0f);
    const bool cross = !(neg || pos);

    const float all_slopes = (su - sl) / (u - l);

    const float s0 = neg ? all_slopes : 0.0f;
    const float s1 = (pos || cross) ? all_slopes : 0.0f;

    const bool neg_slope = (all_slopes < 0.0f);
    float lo = neg_slope ? su : sl;
    float hi = neg_slope ? sl : su;
    lo = cross ? -0.5f : lo;

    float sh1 = fmaf(-s1, u, su);  // su - s1*u
    float sh0 = fmaf(-s0, l, sl);  // sl - s0*l
    sh0 = cross ? -0.5f : sh0;
    sh1 = neg ? sl : sh1;

    const float s1p = fmaxf(s1, 0.0f), s1n = fminf(s1, 0.0f);
    const float s0p = fmaxf(s0, 0.0f), s0n = fminf(s0, 0.0f);

    const float UBM = s1p * p1u + s1n * p1l;
    const float UBV = s1p * q1u + sh1 + s1n * q1l;
    const float LBM = s0p * p1l + s0n * p1u;
    const float LBV = s0n * q1l + sh0 + s0p * q1u;

    const float lower = fmaxf(LBM, 0.0f) * b0l + fminf(LBM, 0.0f) * b0u + LBV;
    const float upper = fmaxf(UBM, 0.0f) * b0u + fminf(UBM, 0.0f) * b0l + UBV;

    out_lo = (lower > lo) ? lower : lo;
    out_hi = (upper < hi) ? upper : hi;
}

__device__ __forceinline__ nfloat4 spu_quad(const nfloat4 b, const nfloat4 sp,
                                            const nfloat4 sh, const nfloat4 bp) {
    float o0, o1, o2, o3;
    spu_row(b.x, b.y, sp.x, sp.y, sh.x, sh.y, bp.x, bp.y, o0, o1);
    spu_row(b.z, b.w, sp.z, sp.w, sh.z, sh.w, bp.z, bp.w, o2, o3);
    nfloat4 o;
    o.x = o0; o.y = o1; o.z = o2; o.w = o3;
    return o;
}

__global__ __launch_bounds__(256) void SPUTransformer_62002147885333_kernel(
    const nfloat4* __restrict__ bounds,
    const nfloat4* __restrict__ slopes_prev,
    const nfloat4* __restrict__ shifts_prev,
    const nfloat4* __restrict__ bounds_prev,
    nfloat4* __restrict__ out,
    int npairs)  // npairs = N/2; one float4 = two (l,u) rows
{
    const int i = blockIdx.x * blockDim.x + threadIdx.x;
    if (i < npairs) {
        // Streaming loads: zero intra-kernel reuse, so skip cache allocation.
        const nfloat4 b  = __builtin_nontemporal_load(&bounds[i]);
        const nfloat4 sp = __builtin_nontemporal_load(&slopes_prev[i]);
        const nfloat4 sh = __builtin_nontemporal_load(&shifts_prev[i]);
        const nfloat4 bp = __builtin_nontemporal_load(&bounds_prev[i]);

        const nfloat4 o = spu_quad(b, sp, sh, bp);

        __builtin_nontemporal_store(o, &out[i]);
    }
}

extern "C" void kernel_launch(void* const* d_in, const int* in_sizes, int n_in,
                              void* d_out, int out_size, void* d_ws, size_t ws_size,
                              hipStream_t stream) {
    // Inputs (setup_inputs order): bounds (N,2), slopes_prev (N,2),
    // shifts_prev (N,2), bounds_prev (N,2) -- all float32.
    const nfloat4* bounds      = (const nfloat4*)d_in[0];
    const nfloat4* slopes_prev = (const nfloat4*)d_in[1];
    const nfloat4* shifts_prev = (const nfloat4*)d_in[2];
    const nfloat4* bounds_prev = (const nfloat4*)d_in[3];
    nfloat4* out = (nfloat4*)d_out;

    const int n_rows = in_sizes[0] / 2;   // N
    const int npairs = n_rows / 2;        // N even (8388608)

    const int block = 256;
    const int grid = (npairs + block - 1) / block;

    SPUTransformer_62002147885333_kernel<<<grid, block, 0, stream>>>(
        bounds, slopes_prev, shifts_prev, bounds_prev, out, npairs);
}